// Round 1
// baseline (1422.255 us; speedup 1.0000x reference)
//
#include <hip/hip_runtime.h>
#include <math.h>

#define D_MODEL 1024
#define TT 4096
#define NB 4
#define NH 16
#define NCH 16

// workspace layout (bytes); peak = 100 MB (full overlays dead Y2)
#define OFF_STATS ((size_t)0)                          // 16384*2 f32 = 128 KB
#define OFF_G     ((size_t)(1 << 20))                  // 64*1024 f32
#define OFF_MM    (OFF_G  + (size_t)64 * 1024 * 4)
#define OFF_CV    (OFF_MM + (size_t)64 * 1024 * 4)     // 64*2048 f32, ends at 2 MB
#define OFF_FT    ((size_t)(2 << 20))                  // 64*2048 f32 = 512 KB
#define OFF_Y1    ((size_t)(4 << 20))                  // 16384*512 f32 = 32 MB
#define OFF_Y2    (OFF_Y1 + (size_t)16384 * 512 * 4)   // up to 64 MB (B*P*1024 f32)
#define OFF_FULL  OFF_Y2                               // 64 MB, overlays Y2 after it is dead

// ---------------- LayerNorm statistics: one block per row ----------------
__global__ __launch_bounds__(256) void ln_stats_k(const float* __restrict__ X,
                                                  float* __restrict__ stats) {
  int r = blockIdx.x;
  const float4 v = ((const float4*)(X + (size_t)r * D_MODEL))[threadIdx.x];
  float s  = v.x + v.y + v.z + v.w;
  float ss = v.x * v.x + v.y * v.y + v.z * v.z + v.w * v.w;
#pragma unroll
  for (int off = 32; off > 0; off >>= 1) {
    s  += __shfl_down(s, off, 64);
    ss += __shfl_down(ss, off, 64);
  }
  __shared__ float as_[4], bs_[4];
  int w = threadIdx.x >> 6, lane = threadIdx.x & 63;
  if (lane == 0) { as_[w] = s; bs_[w] = ss; }
  __syncthreads();
  if (threadIdx.x == 0) {
    float S  = as_[0] + as_[1] + as_[2] + as_[3];
    float SS = bs_[0] + bs_[1] + bs_[2] + bs_[3];
    float mu  = S * (1.0f / D_MODEL);
    float var = SS * (1.0f / D_MODEL) - mu * mu;
    stats[2 * (size_t)r]     = mu;
    stats[2 * (size_t)r + 1] = 1.0f / sqrtf(var + 1e-5f);
  }
}

// ------------- fused LN + projection GEMM (128x128 tile, BK=16) -------------
// mode 0: rows t<P, W=Wk -> Y1 ; mode 1: rows t>=P, W=Wq -> Y1 ;
// mode 2: rows t<P, W=Wv -> Y2 compact (row = b*P+t)
__global__ __launch_bounds__(256) void gemm_ln_k(
    const float* __restrict__ X, const float* __restrict__ stats,
    const float* __restrict__ lng, const float* __restrict__ lnb,
    const float* __restrict__ W, int Nw,
    const int* __restrict__ pref, int mode, float* __restrict__ Y) {
  int P = pref[0]; P = P < 1 ? 1 : (P > TT - 1 ? TT - 1 : P);
  const int b  = blockIdx.z;
  const int t0 = blockIdx.y * 128;
  const int n0 = blockIdx.x * 128;
  if (mode == 1) { if (t0 + 128 <= P) return; }
  else           { if (t0 >= P) return; }
  const int row0 = b * TT + t0;
  __shared__ float As[16 * 132];
  __shared__ float Bs[16 * 128];
  __shared__ float mus[128], rss[128];
  const int tid = threadIdx.x;
  if (tid < 128) {
    mus[tid] = stats[2 * (size_t)(row0 + tid)];
    rss[tid] = stats[2 * (size_t)(row0 + tid) + 1];
  }
  __syncthreads();
  const int tx = tid & 15, ty = tid >> 4;
  float acc[8][8] = {};
  for (int kt = 0; kt < D_MODEL; kt += 16) {
#pragma unroll
    for (int q = 0; q < 2; q++) {
      int f = tid * 2 + q;
      int i = f >> 2, kk = (f & 3) << 2;
      float4 a  = *(const float4*)&X[(size_t)(row0 + i) * D_MODEL + kt + kk];
      float4 g4 = *(const float4*)&lng[kt + kk];
      float4 b4 = *(const float4*)&lnb[kt + kk];
      float mu = mus[i], rs = rss[i];
      As[(kk + 0) * 132 + i] = (a.x - mu) * rs * g4.x + b4.x;
      As[(kk + 1) * 132 + i] = (a.y - mu) * rs * g4.y + b4.y;
      As[(kk + 2) * 132 + i] = (a.z - mu) * rs * g4.z + b4.z;
      As[(kk + 3) * 132 + i] = (a.w - mu) * rs * g4.w + b4.w;
    }
#pragma unroll
    for (int q = 0; q < 2; q++) {
      int f = tid * 2 + q;
      int kk = f >> 5, j = (f & 31) << 2;
      *(float4*)&Bs[kk * 128 + j] = *(const float4*)&W[(size_t)(kt + kk) * Nw + n0 + j];
    }
    __syncthreads();
#pragma unroll
    for (int kk = 0; kk < 16; kk++) {
      float av[8], bv[8];
      *(float4*)&av[0] = *(const float4*)&As[kk * 132 + ty * 8];
      *(float4*)&av[4] = *(const float4*)&As[kk * 132 + ty * 8 + 4];
      *(float4*)&bv[0] = *(const float4*)&Bs[kk * 128 + tx * 8];
      *(float4*)&bv[4] = *(const float4*)&Bs[kk * 128 + tx * 8 + 4];
#pragma unroll
      for (int mi = 0; mi < 8; mi++)
#pragma unroll
        for (int ni = 0; ni < 8; ni++) acc[mi][ni] += av[mi] * bv[ni];
    }
    __syncthreads();
  }
#pragma unroll
  for (int mi = 0; mi < 8; mi++) {
    int t = t0 + ty * 8 + mi;
    bool ok = (mode == 1) ? (t >= P) : (t < P);
    if (!ok) continue;
    size_t orow = (mode == 2) ? ((size_t)b * P + t) : ((size_t)b * TT + t);
    float* dst = &Y[orow * Nw + n0 + tx * 8];
    *(float4*)&dst[0] = make_float4(acc[mi][0], acc[mi][1], acc[mi][2], acc[mi][3]);
    *(float4*)&dst[4] = make_float4(acc[mi][4], acc[mi][5], acc[mi][6], acc[mi][7]);
  }
}

// ------------- G, M, C_v Gram reductions (atomic accumulate) -------------
__global__ __launch_bounds__(256) void build_gmc_k(
    const float* __restrict__ Y1, const float* __restrict__ Y2,
    const int* __restrict__ pref,
    float* __restrict__ G, float* __restrict__ Mm, float* __restrict__ Cv) {
  int P = pref[0]; P = P < 1 ? 1 : (P > TT - 1 ? TT - 1 : P);
  const int bh = blockIdx.y;
  const int b = bh >> 4, h = bh & 15;
  const int tid = threadIdx.x;
  const int chunk = (P + NCH - 1) / NCH;
  const int tb = blockIdx.x * chunk;
  const int te = min(tb + chunk, P);
  if (tb >= te) return;
  __shared__ float kt[129 * 32];  // kt[0] = key[t0-1] (zero when t0==0)
  __shared__ float vt[128 * 64];
  float aG[4] = {}, aM[4] = {}, aC[8] = {};
  const int ii = tid >> 3, j4 = (tid & 7) << 2;
  const int dd = tid >> 2, j8 = (tid & 3) << 3;
  for (int t0 = tb; t0 < te; t0 += 128) {
    const int len = min(128, te - t0);
    __syncthreads();
    for (int e = tid; e < (len + 1) * 8; e += 256) {
      int row = e >> 3, jj = (e & 7) << 2;
      int t = t0 - 1 + row;
      float4 v = make_float4(0.f, 0.f, 0.f, 0.f);
      if (t >= 0) v = *(const float4*)&Y1[((size_t)b * TT + t) * 512 + h * 32 + jj];
      *(float4*)&kt[row * 32 + jj] = v;
    }
    for (int e = tid; e < len * 16; e += 256) {
      int row = e >> 4, dj = (e & 15) << 2;
      int t = t0 + row;
      *(float4*)&vt[row * 64 + dj] =
          *(const float4*)&Y2[((size_t)b * P + t) * 1024 + h * 64 + dj];
    }
    __syncthreads();
    for (int s = 0; s < len; s++) {
      float ki  = kt[(s + 1) * 32 + ii];
      float4 kj = *(const float4*)&kt[(s + 1) * 32 + j4];
      float4 km = *(const float4*)&kt[s * 32 + j4];
      aG[0] += ki * kj.x; aG[1] += ki * kj.y; aG[2] += ki * kj.z; aG[3] += ki * kj.w;
      aM[0] += ki * km.x; aM[1] += ki * km.y; aM[2] += ki * km.z; aM[3] += ki * km.w;
      float vd  = vt[s * 64 + dd];
      float4 ka = *(const float4*)&kt[(s + 1) * 32 + j8];
      float4 kb = *(const float4*)&kt[(s + 1) * 32 + j8 + 4];
      aC[0] += vd * ka.x; aC[1] += vd * ka.y; aC[2] += vd * ka.z; aC[3] += vd * ka.w;
      aC[4] += vd * kb.x; aC[5] += vd * kb.y; aC[6] += vd * kb.z; aC[7] += vd * kb.w;
    }
  }
  float* Gd = &G[(size_t)bh * 1024 + ii * 32 + j4];
  atomicAdd(&Gd[0], aG[0]); atomicAdd(&Gd[1], aG[1]);
  atomicAdd(&Gd[2], aG[2]); atomicAdd(&Gd[3], aG[3]);
  float* Md = &Mm[(size_t)bh * 1024 + ii * 32 + j4];
  atomicAdd(&Md[0], aM[0]); atomicAdd(&Md[1], aM[1]);
  atomicAdd(&Md[2], aM[2]); atomicAdd(&Md[3], aM[3]);
  float* Cd = &Cv[(size_t)bh * 2048 + dd * 32 + j8];
#pragma unroll
  for (int q = 0; q < 8; q++) atomicAdd(&Cd[q], aC[q]);
}

// ------- per-(b,h) operator: chol, G^{-1}, A_w, sigma, F = Cv*Gi*(s*M*Gi)^4 -------
__global__ __launch_bounds__(256) void solve_op_k(
    const float* __restrict__ G, const float* __restrict__ Mm,
    const float* __restrict__ Cv, const float* __restrict__ lridge,
    const float* __restrict__ lgamma, float* __restrict__ Ft) {
  __shared__ float Gs[32 * 33];
  __shared__ float Ms[32 * 32];
  __shared__ float Gi[32 * 32];
  __shared__ float W1[32 * 33];
  __shared__ float Aw[32 * 33];  // holds A_w^T (same singular values / frobenius)
  __shared__ float Nn[32 * 32];
  __shared__ float N2[32 * 32];
  __shared__ float T1[32 * 32];
  __shared__ float Cs[64 * 32];
  __shared__ float red[256];
  __shared__ float vv[32], uu[32];
  const int bh = blockIdx.x;
  const int tid = threadIdx.x;
  const float ridge = expf(lridge[0]);

  for (int e = tid; e < 1024; e += 256) {
    int i = e >> 5, j = e & 31;
    float g = G[(size_t)bh * 1024 + e];
    if (i == j) g += ridge;
    Gs[i * 33 + j] = g;
    Ms[e] = Mm[(size_t)bh * 1024 + e];
  }
  for (int e = tid; e < 2048; e += 256) Cs[e] = Cv[(size_t)bh * 2048 + e];
  __syncthreads();

  // Cholesky, in-place lower, full symmetric trailing update
  for (int j = 0; j < 32; j++) {
    float d = Gs[j * 33 + j];
    __syncthreads();
    float inv = 1.0f / sqrtf(d);
    if (tid >= j && tid < 32) Gs[tid * 33 + j] *= inv;
    __syncthreads();
    int w = 31 - j;
    for (int e = tid; e < w * w; e += 256) {
      int i = j + 1 + e / w, k = j + 1 + e % w;
      Gs[i * 33 + k] -= Gs[i * 33 + j] * Gs[k * 33 + j];
    }
    __syncthreads();
  }

  // Gi = G^{-1} via identity solves (thread = column)
  if (tid < 32) {
    const int c = tid;
    for (int i = 0; i < 32; i++) W1[i * 33 + c] = (i == c) ? 1.0f : 0.0f;
    for (int i = 0; i < 32; i++) {
      float s = W1[i * 33 + c];
      for (int j = 0; j < i; j++) s -= Gs[i * 33 + j] * W1[j * 33 + c];
      W1[i * 33 + c] = s / Gs[i * 33 + i];
    }
    for (int i = 31; i >= 0; i--) {
      float s = W1[i * 33 + c];
      for (int j = i + 1; j < 32; j++) s -= Gs[j * 33 + i] * W1[j * 33 + c];
      W1[i * 33 + c] = s / Gs[i * 33 + i];
    }
    for (int i = 0; i < 32; i++) Gi[i * 32 + c] = W1[i * 33 + c];
  }
  __syncthreads();
  // W1 = L^{-1} M
  if (tid < 32) {
    const int c = tid;
    for (int i = 0; i < 32; i++) {
      float s = Ms[i * 32 + c];
      for (int j = 0; j < i; j++) s -= Gs[i * 33 + j] * W1[j * 33 + c];
      W1[i * 33 + c] = s / Gs[i * 33 + i];
    }
  }
  __syncthreads();
  // Aw (= A_w^T): column c solves L x = (row c of W1)
  if (tid < 32) {
    const int c = tid;
    for (int i = 0; i < 32; i++) {
      float s = W1[c * 33 + i];
      for (int j = 0; j < i; j++) s -= Gs[i * 33 + j] * Aw[j * 33 + c];
      Aw[i * 33 + c] = s / Gs[i * 33 + i];
    }
  }
  __syncthreads();

  // sigma: frobenius fast path (sigma <= ||A||_F); power iteration fallback
  float s0 = 0.0f;
  for (int e = tid; e < 1024; e += 256) {
    float a = Aw[(e >> 5) * 33 + (e & 31)];
    s0 += a * a;
  }
  red[tid] = s0;
  __syncthreads();
  for (int off = 128; off > 0; off >>= 1) {
    if (tid < off) red[tid] += red[tid + off];
    __syncthreads();
  }
  float frob2 = red[0];
  float sigma;
  if (frob2 <= 1.0f) {
    sigma = sqrtf(frob2);  // any value <=1 gives identical scale
  } else {
    if (tid < 32) vv[tid] = 1.0f + 0.001f * (float)tid;
    __syncthreads();
    for (int it = 0; it < 64; it++) {
      if (tid < 32) {
        float s = 0;
        for (int j = 0; j < 32; j++) s += Aw[tid * 33 + j] * vv[j];
        uu[tid] = s;
      }
      __syncthreads();
      if (tid == 0) {
        float n = 0;
        for (int j = 0; j < 32; j++) n += uu[j] * uu[j];
        red[0] = sqrtf(n);
      }
      __syncthreads();
      float nu = fmaxf(red[0], 1e-30f);
      if (tid < 32) uu[tid] /= nu;
      __syncthreads();
      if (tid < 32) {
        float s = 0;
        for (int j = 0; j < 32; j++) s += Aw[j * 33 + tid] * uu[j];
        vv[tid] = s;
      }
      __syncthreads();
      if (tid == 0) {
        float n = 0;
        for (int j = 0; j < 32; j++) n += vv[j] * vv[j];
        red[0] = sqrtf(n);
      }
      __syncthreads();
      float nv = fmaxf(red[0], 1e-30f);
      if (tid < 32) vv[tid] /= nv;
      __syncthreads();
    }
    sigma = red[0];
  }
  float gamma_c = fminf(expf(lgamma[0]), 1.0f);
  float scale = gamma_c / fmaxf(fmaxf(sigma, 1e-8f), 1.0f);

  // Nn = scale * M * Gi ; N4 = Nn^4 (into Ms) ; T1 = Gi * N4 ; Ft = (Cv * T1)^T
  for (int e = tid; e < 1024; e += 256) {
    int i = e >> 5, c = e & 31;
    float s = 0;
#pragma unroll
    for (int k = 0; k < 32; k++) s += Ms[i * 32 + k] * Gi[k * 32 + c];
    Nn[e] = scale * s;
  }
  __syncthreads();
  for (int e = tid; e < 1024; e += 256) {
    int i = e >> 5, c = e & 31;
    float s = 0;
#pragma unroll
    for (int k = 0; k < 32; k++) s += Nn[i * 32 + k] * Nn[k * 32 + c];
    N2[e] = s;
  }
  __syncthreads();
  for (int e = tid; e < 1024; e += 256) {
    int i = e >> 5, c = e & 31;
    float s = 0;
#pragma unroll
    for (int k = 0; k < 32; k++) s += N2[i * 32 + k] * N2[k * 32 + c];
    Ms[e] = s;  // N4
  }
  __syncthreads();
  for (int e = tid; e < 1024; e += 256) {
    int i = e >> 5, c = e & 31;
    float s = 0;
#pragma unroll
    for (int k = 0; k < 32; k++) s += Gi[i * 32 + k] * Ms[k * 32 + c];
    T1[e] = s;
  }
  __syncthreads();
  for (int e = tid; e < 2048; e += 256) {
    int j = e >> 6, d = e & 63;
    float s = 0;
#pragma unroll
    for (int k = 0; k < 32; k++) s += Cs[d * 32 + k] * T1[k * 32 + j];
    Ft[(size_t)bh * 2048 + e] = s;  // Ft[h][j][d]
  }
}

// ------------- apply F^T per (head, 128-token chunk) -------------
__global__ __launch_bounds__(256) void apply_k(const float* __restrict__ Y1,
                                               const float* __restrict__ Ft,
                                               float* __restrict__ full) {
  __shared__ float fs[2048];
  __shared__ float xs[128 * 32];
  const int h = blockIdx.y;
  const int r0 = blockIdx.x * 128;
  const int bh = (r0 >> 12) * NH + h;
  const int tid = threadIdx.x;
  for (int e = tid; e < 2048; e += 256) fs[e] = Ft[(size_t)bh * 2048 + e];
  for (int e = tid; e < 1024; e += 256) {
    int row = e >> 3, j4 = (e & 7) << 2;
    *(float4*)&xs[row * 32 + j4] =
        *(const float4*)&Y1[((size_t)(r0 + row)) * 512 + h * 32 + j4];
  }
  __syncthreads();
  const int d = tid & 63, t0 = tid >> 6;
  for (int tl = t0; tl < 128; tl += 4) {
    float s = 0;
#pragma unroll
    for (int j = 0; j < 32; j++) s += xs[tl * 32 + j] * fs[j * 64 + d];
    full[((size_t)(r0 + tl)) * 1024 + h * 64 + d] = s;
  }
}

// ------------- output GEMM: out = sigmoid(alpha) * full @ Wo -------------
__global__ __launch_bounds__(256) void gemm_out_k(const float* __restrict__ A,
                                                  const float* __restrict__ W,
                                                  const float* __restrict__ alpha,
                                                  float* __restrict__ out) {
  const int m0 = blockIdx.y * 128;
  const int n0 = blockIdx.x * 128;
  __shared__ float As[16 * 132];
  __shared__ float Bs[16 * 128];
  const int tid = threadIdx.x;
  const int tx = tid & 15, ty = tid >> 4;
  float acc[8][8] = {};
  for (int kt = 0; kt < D_MODEL; kt += 16) {
#pragma unroll
    for (int q = 0; q < 2; q++) {
      int f = tid * 2 + q;
      int i = f >> 2, kk = (f & 3) << 2;
      float4 a = *(const float4*)&A[(size_t)(m0 + i) * D_MODEL + kt + kk];
      As[(kk + 0) * 132 + i] = a.x;
      As[(kk + 1) * 132 + i] = a.y;
      As[(kk + 2) * 132 + i] = a.z;
      As[(kk + 3) * 132 + i] = a.w;
    }
#pragma unroll
    for (int q = 0; q < 2; q++) {
      int f = tid * 2 + q;
      int kk = f >> 5, j = (f & 31) << 2;
      *(float4*)&Bs[kk * 128 + j] = *(const float4*)&W[(size_t)(kt + kk) * 1024 + n0 + j];
    }
    __syncthreads();
#pragma unroll
    for (int kk = 0; kk < 16; kk++) {
      float av[8], bv[8];
      *(float4*)&av[0] = *(const float4*)&As[kk * 132 + ty * 8];
      *(float4*)&av[4] = *(const float4*)&As[kk * 132 + ty * 8 + 4];
      *(float4*)&bv[0] = *(const float4*)&Bs[kk * 128 + tx * 8];
      *(float4*)&bv[4] = *(const float4*)&Bs[kk * 128 + tx * 8 + 4];
#pragma unroll
      for (int mi = 0; mi < 8; mi++)
#pragma unroll
        for (int ni = 0; ni < 8; ni++) acc[mi][ni] += av[mi] * bv[ni];
    }
    __syncthreads();
  }
  float sg = 1.0f / (1.0f + expf(-alpha[0]));
#pragma unroll
  for (int mi = 0; mi < 8; mi++) {
    float* dst = &out[(size_t)(m0 + ty * 8 + mi) * 1024 + n0 + tx * 8];
    *(float4*)&dst[0] = make_float4(sg * acc[mi][0], sg * acc[mi][1],
                                    sg * acc[mi][2], sg * acc[mi][3]);
    *(float4*)&dst[4] = make_float4(sg * acc[mi][4], sg * acc[mi][5],
                                    sg * acc[mi][6], sg * acc[mi][7]);
  }
}

extern "C" void kernel_launch(void* const* d_in, const int* in_sizes, int n_in,
                              void* d_out, int out_size, void* d_ws, size_t ws_size,
                              hipStream_t stream) {
  const float* X      = (const float*)d_in[0];
  const float* Wk     = (const float*)d_in[1];
  const float* Wq     = (const float*)d_in[2];
  const float* Wv     = (const float*)d_in[3];
  const float* Wo     = (const float*)d_in[4];
  const float* lng    = (const float*)d_in[5];
  const float* lnb    = (const float*)d_in[6];
  const float* alpha  = (const float*)d_in[7];
  const float* lridge = (const float*)d_in[8];
  const float* lgamma = (const float*)d_in[9];
  const int*   pref   = (const int*)d_in[10];
  float* out = (float*)d_out;
  char* ws = (char*)d_ws;
  float* stats = (float*)(ws + OFF_STATS);
  float* G     = (float*)(ws + OFF_G);
  float* Mm    = (float*)(ws + OFF_MM);
  float* Cv    = (float*)(ws + OFF_CV);
  float* Ft    = (float*)(ws + OFF_FT);
  float* Y1    = (float*)(ws + OFF_Y1);
  float* Y2    = (float*)(ws + OFF_Y2);
  float* full  = (float*)(ws + OFF_FULL);

  hipMemsetAsync(ws + OFF_G, 0, 1 << 20, stream);  // zero G, M, Cv
  ln_stats_k<<<16384, 256, 0, stream>>>(X, stats);
  gemm_ln_k<<<dim3(4, 32, NB), 256, 0, stream>>>(X, stats, lng, lnb, Wk, 512, pref, 0, Y1);
  gemm_ln_k<<<dim3(4, 32, NB), 256, 0, stream>>>(X, stats, lng, lnb, Wq, 512, pref, 1, Y1);
  gemm_ln_k<<<dim3(8, 32, NB), 256, 0, stream>>>(X, stats, lng, lnb, Wv, 1024, pref, 2, Y2);
  build_gmc_k<<<dim3(NCH, 64), 256, 0, stream>>>(Y1, Y2, pref, G, Mm, Cv);
  solve_op_k<<<64, 256, 0, stream>>>(G, Mm, Cv, lridge, lgamma, Ft);
  apply_k<<<dim3(128, NH), 256, 0, stream>>>(Y1, Ft, full);
  gemm_out_k<<<dim3(8, 128), 256, 0, stream>>>(full, Wo, alpha, out);
}

// Round 2
// 657.641 us; speedup vs baseline: 2.1627x; 2.1627x over previous
//
#include <hip/hip_runtime.h>
#include <math.h>

#define D_MODEL 1024
#define TT 4096
#define NB 4
#define NH 16
#define NCH 16

typedef __attribute__((ext_vector_type(8))) short s8v;
typedef __attribute__((ext_vector_type(4))) float f4v;
typedef __attribute__((ext_vector_type(8))) unsigned short u16x8;

// ---- workspace layout (bytes); peak 80 MB (proven budget was 100 MB) ----
#define OFF_STATS ((size_t)0)
#define OFF_G     ((size_t)(1 << 20))
#define OFF_MM    (OFF_G + (size_t)(256 << 10))
#define OFF_CV    (OFF_MM + (size_t)(256 << 10))
#define OFF_FT    ((size_t)(2 << 20))
#define OFF_WKH   ((size_t)(4 << 20))
#define OFF_WKL   ((size_t)(5 << 20))
#define OFF_WQH   ((size_t)(6 << 20))
#define OFF_WQL   ((size_t)(7 << 20))
#define OFF_WVH   ((size_t)(8 << 20))
#define OFF_WVL   ((size_t)(10 << 20))
#define OFF_WOH   ((size_t)(12 << 20))
#define OFF_WOL   ((size_t)(14 << 20))
#define OFF_Y1    ((size_t)(16 << 20))
#define OFF_Y2    ((size_t)(48 << 20))   // 32 MB; full_hi overlays after build_gmc
#define OFF_FH    OFF_Y2

__device__ __forceinline__ unsigned short bf16_rne(float x) {
  unsigned u = __float_as_uint(x);
  return (unsigned short)((u + 0x7fffu + ((u >> 16) & 1u)) >> 16);
}
__device__ __forceinline__ void split_bf16(float x, unsigned short& h, unsigned short& l) {
  unsigned u = __float_as_uint(x);
  unsigned r = (u + 0x7fffu + ((u >> 16) & 1u)) & 0xffff0000u;
  h = (unsigned short)(r >> 16);
  float res = x - __uint_as_float(r);
  l = bf16_rne(res);
}

// ---------------- LayerNorm statistics: one block per row ----------------
__global__ __launch_bounds__(256) void ln_stats_k(const float* __restrict__ X,
                                                  float* __restrict__ stats) {
  int r = blockIdx.x;
  const float4 v = ((const float4*)(X + (size_t)r * D_MODEL))[threadIdx.x];
  float s  = v.x + v.y + v.z + v.w;
  float ss = v.x * v.x + v.y * v.y + v.z * v.z + v.w * v.w;
#pragma unroll
  for (int off = 32; off > 0; off >>= 1) {
    s  += __shfl_down(s, off, 64);
    ss += __shfl_down(ss, off, 64);
  }
  __shared__ float as_[4], bs_[4];
  int w = threadIdx.x >> 6, lane = threadIdx.x & 63;
  if (lane == 0) { as_[w] = s; bs_[w] = ss; }
  __syncthreads();
  if (threadIdx.x == 0) {
    float S  = as_[0] + as_[1] + as_[2] + as_[3];
    float SS = bs_[0] + bs_[1] + bs_[2] + bs_[3];
    float mu  = S * (1.0f / D_MODEL);
    float var = SS * (1.0f / D_MODEL) - mu * mu;
    stats[2 * (size_t)r]     = mu;
    stats[2 * (size_t)r + 1] = 1.0f / sqrtf(var + 1e-5f);
  }
}

// ------- prep: transpose W[K][N] -> WT_hi/lo [N][K] bf16 split -------
__global__ __launch_bounds__(256) void prep_w_k(const float* __restrict__ W, int N,
                                                unsigned short* __restrict__ Thi,
                                                unsigned short* __restrict__ Tlo) {
  __shared__ float tileT[32 * 33];
  const int n0 = blockIdx.x * 32, k0 = blockIdx.y * 32;
  const int tid = threadIdx.x;
  {
    int k_l = tid >> 3, n4 = (tid & 7) << 2;
    float4 v = *(const float4*)&W[(size_t)(k0 + k_l) * N + n0 + n4];
    tileT[(n4 + 0) * 33 + k_l] = v.x;
    tileT[(n4 + 1) * 33 + k_l] = v.y;
    tileT[(n4 + 2) * 33 + k_l] = v.z;
    tileT[(n4 + 3) * 33 + k_l] = v.w;
  }
  __syncthreads();
  {
    int n_l = tid >> 3, k4 = (tid & 7) << 2;
    unsigned short h[4], l[4];
#pragma unroll
    for (int i = 0; i < 4; i++) split_bf16(tileT[n_l * 33 + k4 + i], h[i], l[i]);
    *(ushort4*)&Thi[(size_t)(n0 + n_l) * 1024 + k0 + k4] = make_ushort4(h[0], h[1], h[2], h[3]);
    *(ushort4*)&Tlo[(size_t)(n0 + n_l) * 1024 + k0 + k4] = make_ushort4(l[0], l[1], l[2], l[3]);
  }
}

// ------- fused LN + projection GEMM, split-bf16 MFMA (3 products) -------
// mode 0: rows t<P, Wk -> Y1 ; mode 1: rows t>=P, Wq -> Y1 ; mode 2: rows t<P, Wv -> Y2 compact
__global__ __launch_bounds__(256) void gemm_proj_k(
    const float* __restrict__ X, const float* __restrict__ stats,
    const float* __restrict__ lng, const float* __restrict__ lnb,
    const unsigned short* __restrict__ WThi, const unsigned short* __restrict__ WTlo,
    int Nw, const int* __restrict__ pref, int mode, float* __restrict__ Y) {
  int P = pref[0]; P = P < 1 ? 1 : (P > TT - 1 ? TT - 1 : P);
  const int b  = blockIdx.z;
  const int t0 = blockIdx.y * 128;
  const int n0 = blockIdx.x * 128;
  if (mode == 1) { if (t0 + 128 <= P) return; }
  else           { if (t0 >= P) return; }
  const int row0 = b * TT + t0;
  __shared__ __align__(16) unsigned short Ah[128 * 40], Al[128 * 40];
  __shared__ __align__(16) unsigned short Bh[128 * 40], Bl[128 * 40];
  __shared__ float mus[128], rss[128];
  const int tid = threadIdx.x;
  if (tid < 128) {
    mus[tid] = stats[2 * (size_t)(row0 + tid)];
    rss[tid] = stats[2 * (size_t)(row0 + tid) + 1];
  }
  const int lane = tid & 63;
  const int wm = ((tid >> 6) >> 1) * 64, wn = ((tid >> 6) & 1) * 64;
  const int lm = lane & 15, lq = lane >> 4;
  f4v acc[4][4];
#pragma unroll
  for (int i = 0; i < 4; i++)
#pragma unroll
    for (int j = 0; j < 4; j++) acc[i][j] = (f4v){0.f, 0.f, 0.f, 0.f};

  for (int kt = 0; kt < D_MODEL; kt += 32) {
    __syncthreads();
#pragma unroll
    for (int q = 0; q < 2; q++) {
      int c = tid * 2 + q;
      int m = c >> 2, k8 = (c & 3) << 3;
      const float* src = &X[(size_t)(row0 + m) * D_MODEL + kt + k8];
      float mu = mus[m], rs = rss[m];
      u16x8 hv, lv;
#pragma unroll
      for (int i = 0; i < 8; i++) {
        float nv = (src[i] - mu) * rs * lng[kt + k8 + i] + lnb[kt + k8 + i];
        unsigned short h, l;
        split_bf16(nv, h, l);
        hv[i] = h; lv[i] = l;
      }
      *(u16x8*)&Ah[m * 40 + k8] = hv;
      *(u16x8*)&Al[m * 40 + k8] = lv;
      *(u16x8*)&Bh[m * 40 + k8] = *(const u16x8*)&WThi[(size_t)(n0 + m) * 1024 + kt + k8];
      *(u16x8*)&Bl[m * 40 + k8] = *(const u16x8*)&WTlo[(size_t)(n0 + m) * 1024 + kt + k8];
    }
    __syncthreads();
    s8v ah[4], al[4], bh[4], bl[4];
#pragma unroll
    for (int i = 0; i < 4; i++) {
      int ar = (wm + i * 16 + lm) * 40 + lq * 8;
      int br = (wn + i * 16 + lm) * 40 + lq * 8;
      ah[i] = *(const s8v*)&Ah[ar];
      al[i] = *(const s8v*)&Al[ar];
      bh[i] = *(const s8v*)&Bh[br];
      bl[i] = *(const s8v*)&Bl[br];
    }
#pragma unroll
    for (int mi = 0; mi < 4; mi++)
#pragma unroll
      for (int ni = 0; ni < 4; ni++) {
        acc[mi][ni] = __builtin_amdgcn_mfma_f32_16x16x32_bf16(ah[mi], bh[ni], acc[mi][ni], 0, 0, 0);
        acc[mi][ni] = __builtin_amdgcn_mfma_f32_16x16x32_bf16(ah[mi], bl[ni], acc[mi][ni], 0, 0, 0);
        acc[mi][ni] = __builtin_amdgcn_mfma_f32_16x16x32_bf16(al[mi], bh[ni], acc[mi][ni], 0, 0, 0);
      }
  }
#pragma unroll
  for (int mi = 0; mi < 4; mi++) {
#pragma unroll
    for (int r = 0; r < 4; r++) {
      int t = t0 + wm + mi * 16 + lq * 4 + r;
      bool ok = (mode == 1) ? (t >= P) : (t < P);
      if (!ok) continue;
      size_t orow = (mode == 2) ? ((size_t)b * P + t) : ((size_t)b * TT + t);
#pragma unroll
      for (int ni = 0; ni < 4; ni++)
        Y[orow * Nw + n0 + wn + ni * 16 + lm] = acc[mi][ni][r];
    }
  }
}

// ------------- G, M, C_v Gram reductions (atomic accumulate) -------------
__global__ __launch_bounds__(256) void build_gmc_k(
    const float* __restrict__ Y1, const float* __restrict__ Y2,
    const int* __restrict__ pref,
    float* __restrict__ G, float* __restrict__ Mm, float* __restrict__ Cv) {
  int P = pref[0]; P = P < 1 ? 1 : (P > TT - 1 ? TT - 1 : P);
  const int bh = blockIdx.y;
  const int b = bh >> 4, h = bh & 15;
  const int tid = threadIdx.x;
  const int chunk = (P + NCH - 1) / NCH;
  const int tb = blockIdx.x * chunk;
  const int te = min(tb + chunk, P);
  if (tb >= te) return;
  __shared__ float kt[129 * 32];
  __shared__ float vt[128 * 64];
  float aG[4] = {}, aM[4] = {}, aC[8] = {};
  const int ii = tid >> 3, j4 = (tid & 7) << 2;
  const int dd = tid >> 2, j8 = (tid & 3) << 3;
  for (int t0 = tb; t0 < te; t0 += 128) {
    const int len = min(128, te - t0);
    __syncthreads();
    for (int e = tid; e < (len + 1) * 8; e += 256) {
      int row = e >> 3, jj = (e & 7) << 2;
      int t = t0 - 1 + row;
      float4 v = make_float4(0.f, 0.f, 0.f, 0.f);
      if (t >= 0) v = *(const float4*)&Y1[((size_t)b * TT + t) * 512 + h * 32 + jj];
      *(float4*)&kt[row * 32 + jj] = v;
    }
    for (int e = tid; e < len * 16; e += 256) {
      int row = e >> 4, dj = (e & 15) << 2;
      int t = t0 + row;
      *(float4*)&vt[row * 64 + dj] =
          *(const float4*)&Y2[((size_t)b * P + t) * 1024 + h * 64 + dj];
    }
    __syncthreads();
    for (int s = 0; s < len; s++) {
      float ki  = kt[(s + 1) * 32 + ii];
      float4 kj = *(const float4*)&kt[(s + 1) * 32 + j4];
      float4 km = *(const float4*)&kt[s * 32 + j4];
      aG[0] += ki * kj.x; aG[1] += ki * kj.y; aG[2] += ki * kj.z; aG[3] += ki * kj.w;
      aM[0] += ki * km.x; aM[1] += ki * km.y; aM[2] += ki * km.z; aM[3] += ki * km.w;
      float vd  = vt[s * 64 + dd];
      float4 ka = *(const float4*)&kt[(s + 1) * 32 + j8];
      float4 kb = *(const float4*)&kt[(s + 1) * 32 + j8 + 4];
      aC[0] += vd * ka.x; aC[1] += vd * ka.y; aC[2] += vd * ka.z; aC[3] += vd * ka.w;
      aC[4] += vd * kb.x; aC[5] += vd * kb.y; aC[6] += vd * kb.z; aC[7] += vd * kb.w;
    }
  }
  float* Gd = &G[(size_t)bh * 1024 + ii * 32 + j4];
  atomicAdd(&Gd[0], aG[0]); atomicAdd(&Gd[1], aG[1]);
  atomicAdd(&Gd[2], aG[2]); atomicAdd(&Gd[3], aG[3]);
  float* Md = &Mm[(size_t)bh * 1024 + ii * 32 + j4];
  atomicAdd(&Md[0], aM[0]); atomicAdd(&Md[1], aM[1]);
  atomicAdd(&Md[2], aM[2]); atomicAdd(&Md[3], aM[3]);
  float* Cd = &Cv[(size_t)bh * 2048 + dd * 32 + j8];
#pragma unroll
  for (int q = 0; q < 8; q++) atomicAdd(&Cd[q], aC[q]);
}

// ------- per-(b,h) operator: chol, G^{-1}, A_w, sigma, F = Cv*Gi*(s*M*Gi)^4 -------
__global__ __launch_bounds__(256) void solve_op_k(
    const float* __restrict__ G, const float* __restrict__ Mm,
    const float* __restrict__ Cv, const float* __restrict__ lridge,
    const float* __restrict__ lgamma, float* __restrict__ Ft) {
  __shared__ float Gs[32 * 33];
  __shared__ float Ms[32 * 32];
  __shared__ float Gi[32 * 32];
  __shared__ float W1[32 * 33];
  __shared__ float Aw[32 * 33];
  __shared__ float Nn[32 * 32];
  __shared__ float N2[32 * 32];
  __shared__ float T1[32 * 32];
  __shared__ float Cs[64 * 32];
  __shared__ float red[256];
  __shared__ float vv[32], uu[32];
  const int bh = blockIdx.x;
  const int tid = threadIdx.x;
  const float ridge = expf(lridge[0]);

  for (int e = tid; e < 1024; e += 256) {
    int i = e >> 5, j = e & 31;
    float g = G[(size_t)bh * 1024 + e];
    if (i == j) g += ridge;
    Gs[i * 33 + j] = g;
    Ms[e] = Mm[(size_t)bh * 1024 + e];
  }
  for (int e = tid; e < 2048; e += 256) Cs[e] = Cv[(size_t)bh * 2048 + e];
  __syncthreads();

  for (int j = 0; j < 32; j++) {
    float d = Gs[j * 33 + j];
    __syncthreads();
    float inv = 1.0f / sqrtf(d);
    if (tid >= j && tid < 32) Gs[tid * 33 + j] *= inv;
    __syncthreads();
    int w = 31 - j;
    for (int e = tid; e < w * w; e += 256) {
      int i = j + 1 + e / w, k = j + 1 + e % w;
      Gs[i * 33 + k] -= Gs[i * 33 + j] * Gs[k * 33 + j];
    }
    __syncthreads();
  }

  if (tid < 32) {
    const int c = tid;
    for (int i = 0; i < 32; i++) W1[i * 33 + c] = (i == c) ? 1.0f : 0.0f;
    for (int i = 0; i < 32; i++) {
      float s = W1[i * 33 + c];
      for (int j = 0; j < i; j++) s -= Gs[i * 33 + j] * W1[j * 33 + c];
      W1[i * 33 + c] = s / Gs[i * 33 + i];
    }
    for (int i = 31; i >= 0; i--) {
      float s = W1[i * 33 + c];
      for (int j = i + 1; j < 32; j++) s -= Gs[j * 33 + i] * W1[j * 33 + c];
      W1[i * 33 + c] = s / Gs[i * 33 + i];
    }
    for (int i = 0; i < 32; i++) Gi[i * 32 + c] = W1[i * 33 + c];
  }
  __syncthreads();
  if (tid < 32) {
    const int c = tid;
    for (int i = 0; i < 32; i++) {
      float s = Ms[i * 32 + c];
      for (int j = 0; j < i; j++) s -= Gs[i * 33 + j] * W1[j * 33 + c];
      W1[i * 33 + c] = s / Gs[i * 33 + i];
    }
  }
  __syncthreads();
  if (tid < 32) {
    const int c = tid;
    for (int i = 0; i < 32; i++) {
      float s = W1[c * 33 + i];
      for (int j = 0; j < i; j++) s -= Gs[i * 33 + j] * Aw[j * 33 + c];
      Aw[i * 33 + c] = s / Gs[i * 33 + i];
    }
  }
  __syncthreads();

  float s0 = 0.0f;
  for (int e = tid; e < 1024; e += 256) {
    float a = Aw[(e >> 5) * 33 + (e & 31)];
    s0 += a * a;
  }
  red[tid] = s0;
  __syncthreads();
  for (int off = 128; off > 0; off >>= 1) {
    if (tid < off) red[tid] += red[tid + off];
    __syncthreads();
  }
  float frob2 = red[0];
  float sigma;
  if (frob2 <= 1.0f) {
    sigma = sqrtf(frob2);
  } else {
    if (tid < 32) vv[tid] = 1.0f + 0.001f * (float)tid;
    __syncthreads();
    for (int it = 0; it < 64; it++) {
      if (tid < 32) {
        float s = 0;
        for (int j = 0; j < 32; j++) s += Aw[tid * 33 + j] * vv[j];
        uu[tid] = s;
      }
      __syncthreads();
      if (tid == 0) {
        float n = 0;
        for (int j = 0; j < 32; j++) n += uu[j] * uu[j];
        red[0] = sqrtf(n);
      }
      __syncthreads();
      float nu = fmaxf(red[0], 1e-30f);
      if (tid < 32) uu[tid] /= nu;
      __syncthreads();
      if (tid < 32) {
        float s = 0;
        for (int j = 0; j < 32; j++) s += Aw[j * 33 + tid] * uu[j];
        vv[tid] = s;
      }
      __syncthreads();
      if (tid == 0) {
        float n = 0;
        for (int j = 0; j < 32; j++) n += vv[j] * vv[j];
        red[0] = sqrtf(n);
      }
      __syncthreads();
      float nv = fmaxf(red[0], 1e-30f);
      if (tid < 32) vv[tid] /= nv;
      __syncthreads();
    }
    sigma = red[0];
  }
  float gamma_c = fminf(expf(lgamma[0]), 1.0f);
  float scale = gamma_c / fmaxf(fmaxf(sigma, 1e-8f), 1.0f);

  for (int e = tid; e < 1024; e += 256) {
    int i = e >> 5, c = e & 31;
    float s = 0;
#pragma unroll
    for (int k = 0; k < 32; k++) s += Ms[i * 32 + k] * Gi[k * 32 + c];
    Nn[e] = scale * s;
  }
  __syncthreads();
  for (int e = tid; e < 1024; e += 256) {
    int i = e >> 5, c = e & 31;
    float s = 0;
#pragma unroll
    for (int k = 0; k < 32; k++) s += Nn[i * 32 + k] * Nn[k * 32 + c];
    N2[e] = s;
  }
  __syncthreads();
  for (int e = tid; e < 1024; e += 256) {
    int i = e >> 5, c = e & 31;
    float s = 0;
#pragma unroll
    for (int k = 0; k < 32; k++) s += N2[i * 32 + k] * N2[k * 32 + c];
    Ms[e] = s;
  }
  __syncthreads();
  for (int e = tid; e < 1024; e += 256) {
    int i = e >> 5, c = e & 31;
    float s = 0;
#pragma unroll
    for (int k = 0; k < 32; k++) s += Gi[i * 32 + k] * Ms[k * 32 + c];
    T1[e] = s;
  }
  __syncthreads();
  for (int e = tid; e < 2048; e += 256) {
    int j = e >> 6, d = e & 63;
    float s = 0;
#pragma unroll
    for (int k = 0; k < 32; k++) s += Cs[d * 32 + k] * T1[k * 32 + j];
    Ft[(size_t)bh * 2048 + e] = s;
  }
}

// ------------- apply F^T per (head, 128-token chunk) -> full_hi (bf16) -------------
__global__ __launch_bounds__(256) void apply_k(const float* __restrict__ Y1,
                                               const float* __restrict__ Ft,
                                               unsigned short* __restrict__ FH) {
  __shared__ float fs[2048];
  __shared__ float xs[128 * 32];
  const int h = blockIdx.y;
  const int r0 = blockIdx.x * 128;
  const int bh = (r0 >> 12) * NH + h;
  const int tid = threadIdx.x;
  for (int e = tid; e < 2048; e += 256) fs[e] = Ft[(size_t)bh * 2048 + e];
  for (int e = tid; e < 1024; e += 256) {
    int row = e >> 3, j4 = (e & 7) << 2;
    *(float4*)&xs[row * 32 + j4] =
        *(const float4*)&Y1[((size_t)(r0 + row)) * 512 + h * 32 + j4];
  }
  __syncthreads();
  const int d = tid & 63, t0 = tid >> 6;
  for (int tl = t0; tl < 128; tl += 4) {
    float s = 0;
#pragma unroll
    for (int j = 0; j < 32; j++) s += xs[tl * 32 + j] * fs[j * 64 + d];
    FH[((size_t)(r0 + tl)) * 1024 + h * 64 + d] = bf16_rne(s);
  }
}

// ------------- output GEMM (MFMA): out = sg * full @ Wo ; A=hi, B=hi+lo -------------
__global__ __launch_bounds__(256) void gemm_out_k(
    const unsigned short* __restrict__ FH,
    const unsigned short* __restrict__ WThi, const unsigned short* __restrict__ WTlo,
    const float* __restrict__ alpha, float* __restrict__ out) {
  const int m0 = blockIdx.y * 128;
  const int n0 = blockIdx.x * 128;
  __shared__ __align__(16) unsigned short Ah[128 * 40];
  __shared__ __align__(16) unsigned short Bh[128 * 40], Bl[128 * 40];
  const int tid = threadIdx.x;
  const int lane = tid & 63;
  const int wm = ((tid >> 6) >> 1) * 64, wn = ((tid >> 6) & 1) * 64;
  const int lm = lane & 15, lq = lane >> 4;
  f4v acc[4][4];
#pragma unroll
  for (int i = 0; i < 4; i++)
#pragma unroll
    for (int j = 0; j < 4; j++) acc[i][j] = (f4v){0.f, 0.f, 0.f, 0.f};

  for (int kt = 0; kt < D_MODEL; kt += 32) {
    __syncthreads();
#pragma unroll
    for (int q = 0; q < 2; q++) {
      int c = tid * 2 + q;
      int m = c >> 2, k8 = (c & 3) << 3;
      *(u16x8*)&Ah[m * 40 + k8] = *(const u16x8*)&FH[(size_t)(m0 + m) * 1024 + kt + k8];
      *(u16x8*)&Bh[m * 40 + k8] = *(const u16x8*)&WThi[(size_t)(n0 + m) * 1024 + kt + k8];
      *(u16x8*)&Bl[m * 40 + k8] = *(const u16x8*)&WTlo[(size_t)(n0 + m) * 1024 + kt + k8];
    }
    __syncthreads();
    s8v ah[4], bh[4], bl[4];
#pragma unroll
    for (int i = 0; i < 4; i++) {
      ah[i] = *(const s8v*)&Ah[(wm + i * 16 + lm) * 40 + lq * 8];
      bh[i] = *(const s8v*)&Bh[(wn + i * 16 + lm) * 40 + lq * 8];
      bl[i] = *(const s8v*)&Bl[(wn + i * 16 + lm) * 40 + lq * 8];
    }
#pragma unroll
    for (int mi = 0; mi < 4; mi++)
#pragma unroll
      for (int ni = 0; ni < 4; ni++) {
        acc[mi][ni] = __builtin_amdgcn_mfma_f32_16x16x32_bf16(ah[mi], bh[ni], acc[mi][ni], 0, 0, 0);
        acc[mi][ni] = __builtin_amdgcn_mfma_f32_16x16x32_bf16(ah[mi], bl[ni], acc[mi][ni], 0, 0, 0);
      }
  }
  float sg = 1.0f / (1.0f + expf(-alpha[0]));
#pragma unroll
  for (int mi = 0; mi < 4; mi++)
#pragma unroll
    for (int r = 0; r < 4; r++) {
      size_t orow = (size_t)(m0 + wm + mi * 16 + lq * 4 + r);
#pragma unroll
      for (int ni = 0; ni < 4; ni++)
        out[orow * 1024 + n0 + wn + ni * 16 + lm] = sg * acc[mi][ni][r];
    }
}

extern "C" void kernel_launch(void* const* d_in, const int* in_sizes, int n_in,
                              void* d_out, int out_size, void* d_ws, size_t ws_size,
                              hipStream_t stream) {
  const float* X      = (const float*)d_in[0];
  const float* Wk     = (const float*)d_in[1];
  const float* Wq     = (const float*)d_in[2];
  const float* Wv     = (const float*)d_in[3];
  const float* Wo     = (const float*)d_in[4];
  const float* lng    = (const float*)d_in[5];
  const float* lnb    = (const float*)d_in[6];
  const float* alpha  = (const float*)d_in[7];
  const float* lridge = (const float*)d_in[8];
  const float* lgamma = (const float*)d_in[9];
  const int*   pref   = (const int*)d_in[10];
  float* out = (float*)d_out;
  char* ws = (char*)d_ws;
  float* stats = (float*)(ws + OFF_STATS);
  float* G     = (float*)(ws + OFF_G);
  float* Mm    = (float*)(ws + OFF_MM);
  float* Cv    = (float*)(ws + OFF_CV);
  float* Ft    = (float*)(ws + OFF_FT);
  unsigned short* WKH = (unsigned short*)(ws + OFF_WKH);
  unsigned short* WKL = (unsigned short*)(ws + OFF_WKL);
  unsigned short* WQH = (unsigned short*)(ws + OFF_WQH);
  unsigned short* WQL = (unsigned short*)(ws + OFF_WQL);
  unsigned short* WVH = (unsigned short*)(ws + OFF_WVH);
  unsigned short* WVL = (unsigned short*)(ws + OFF_WVL);
  unsigned short* WOH = (unsigned short*)(ws + OFF_WOH);
  unsigned short* WOL = (unsigned short*)(ws + OFF_WOL);
  float* Y1 = (float*)(ws + OFF_Y1);
  float* Y2 = (float*)(ws + OFF_Y2);
  unsigned short* FH = (unsigned short*)(ws + OFF_FH);

  hipMemsetAsync(ws + OFF_G, 0, 1 << 20, stream);
  ln_stats_k<<<16384, 256, 0, stream>>>(X, stats);
  prep_w_k<<<dim3(16, 32), 256, 0, stream>>>(Wk, 512, WKH, WKL);
  prep_w_k<<<dim3(16, 32), 256, 0, stream>>>(Wq, 512, WQH, WQL);
  prep_w_k<<<dim3(32, 32), 256, 0, stream>>>(Wv, 1024, WVH, WVL);
  prep_w_k<<<dim3(32, 32), 256, 0, stream>>>(Wo, 1024, WOH, WOL);
  gemm_proj_k<<<dim3(4, 32, NB), 256, 0, stream>>>(X, stats, lng, lnb, WKH, WKL, 512, pref, 0, Y1);
  gemm_proj_k<<<dim3(4, 32, NB), 256, 0, stream>>>(X, stats, lng, lnb, WQH, WQL, 512, pref, 1, Y1);
  gemm_proj_k<<<dim3(8, 32, NB), 256, 0, stream>>>(X, stats, lng, lnb, WVH, WVL, 1024, pref, 2, Y2);
  build_gmc_k<<<dim3(NCH, 64), 256, 0, stream>>>(Y1, Y2, pref, G, Mm, Cv);
  solve_op_k<<<64, 256, 0, stream>>>(G, Mm, Cv, lridge, lgamma, Ft);
  apply_k<<<dim3(128, NH), 256, 0, stream>>>(Y1, Ft, FH);
  gemm_out_k<<<dim3(8, 128), 256, 0, stream>>>(FH, WOH, WOL, alpha, out);
}